// Round 6
// baseline (251.414 us; speedup 1.0000x reference)
//
#include <hip/hip_runtime.h>
#include <hip/hip_bf16.h>
#include <stdint.h>

// Problem constants (all inputs & output are FP32 per the reference file)
#define BATCH 128
#define LAT   2000
#define NG    10000
#define KW    20
#define OUTW  (NG * KW)   // 200000
#define EPSV  1e-5f

#define NKT   32            // 64-wide k-tiles in padded z (2048 = 32*64)
#define EG    16            // groups per block (NG = 625 * 16 exactly)
#define HR_STRIDE 132       // h LDS row stride (floats): <=2-way bank alias

typedef __bf16 bf16x8 __attribute__((ext_vector_type(8)));
typedef float  f32x4  __attribute__((ext_vector_type(4)));

__device__ __forceinline__ ushort f2bf(float f) {
  uint32_t u = __builtin_bit_cast(uint32_t, f);
  u = (u + 0x7FFFu + ((u >> 16) & 1u)) >> 16;  // RNE
  return (ushort)u;
}

__device__ __forceinline__ int4 pack8(const float* p) {
  float4 f0 = *(const float4*)p;
  float4 f1 = *(const float4*)(p + 4);
  int4 v;
  v.x = (int)((uint32_t)f2bf(f0.x) | ((uint32_t)f2bf(f0.y) << 16));
  v.y = (int)((uint32_t)f2bf(f0.z) | ((uint32_t)f2bf(f0.w) << 16));
  v.z = (int)((uint32_t)f2bf(f1.x) | ((uint32_t)f2bf(f1.y) << 16));
  v.w = (int)((uint32_t)f2bf(f1.z) | ((uint32_t)f2bf(f1.w) << 16));
  return v;
}

// native packed RNE f32->bf16 (compiler emits v_cvt_pk_bf16_f32 pairs)
__device__ __forceinline__ bf16x8 cvt8(float4 a, float4 b) {
  bf16x8 r;
  r[0] = (__bf16)a.x; r[1] = (__bf16)a.y; r[2] = (__bf16)a.z; r[3] = (__bf16)a.w;
  r[4] = (__bf16)b.x; r[5] = (__bf16)b.y; r[6] = (__bf16)b.z; r[7] = (__bf16)b.w;
  return r;
}

// =====================================================================
// Phase 0: z (128 x 2000 f32) -> bf16 image permuted to WAVE-COALESCED
// fragment order: chunk index ((kt*2+kk)*8 + wave)*64 + q*16 + cl holds
// z[wave*16+cl][kt*64 + kk*32 + q*8 .. +8]. In the GEMM, a wave's 64
// lanes (lane = q*16+cl) read 64 CONSECUTIVE chunks -> 1 KB coalesced.
// Zero-padded above k=2000 (this zero-ness also covers the W tail).
// =====================================================================
__global__ __launch_bounds__(256) void zprep_kernel(
    const float* __restrict__ zp, int4* __restrict__ zlin) {
  const int cg = blockIdx.x * 256 + threadIdx.x;   // 0..32767
  const int r  = cg >> 8;        // batch row 0..127
  const int ck = cg & 255;       // 16B chunk in row; k0 = ck*8
  const int k0 = ck * 8;
  int4 v = make_int4(0, 0, 0, 0);
  if (k0 < LAT) v = pack8(zp + (size_t)r * LAT + k0);  // LAT%8==0: no straddle
  const int kt = ck >> 3, kk = (ck >> 2) & 1, q = ck & 3;
  const int dst = ((kt * 2 + kk) * 8 + (r >> 4)) * 64 + q * 16 + (r & 15);
  zlin[dst] = v;
}

// =====================================================================
// Fused pipeline, fully LDS-free barrier-free GEMM phase.
// One block = 16 groups x all 128 batches; 512 threads = 8 waves, wave w
// owns batches w*16..w*16+15 (B operand from the permuted z image: 64
// consecutive 16B chunks per wave-load = 1 KB coalesced, L2-hot).
// A-fragments load DIRECTLY from W global in per-wave fragment order:
// lane q*16+cl reads row g0+cl at k+q*8 -> one instruction touches 16
// rows x 64 B = 16 fully-consumed cache lines; the 8 waves' identical
// A-reads merge in L1. f32->bf16 cvt in registers; 1-tile software
// pipeline in named registers. K-tail: W address clamped in-row, the
// z image is zero there so garbage x 0 = 0.
// No LDS, no barriers, no bank conflicts in the k-loop; LDS ~10 KB ->
// occupancy is VGPR-bound: __launch_bounds__(512,6) targets 24 waves/CU.
// Then: h -> LDS -> BN stats -> store-coalesced expand (2 barriers).
// =====================================================================
__global__ __launch_bounds__(512, 6) void fused16_kernel(
    const int4* __restrict__ zlin, const float* __restrict__ wp,
    const float* __restrict__ gammap, const float* __restrict__ betap,
    const float* __restrict__ convwp, const float* __restrict__ convbp,
    float* __restrict__ out) {
  const int tid = threadIdx.x;
  const int g0  = blockIdx.x * EG;

  __shared__ float  h_raw[EG * HR_STRIDE];   // raw (pre-BN) h
  __shared__ float4 cw_s[EG * 5];            // conv_w window
  __shared__ float  cb_s[EG];
  __shared__ float  scale_s[EG];
  __shared__ float  shift_s[EG];

  if (tid < EG * 5)
    cw_s[tid] = *(const float4*)(convwp + (size_t)g0 * KW + tid * 4);
  if (tid < EG) cb_s[tid] = convbp[g0 + tid];

  const int lane = tid & 63;
  const int w    = tid >> 6;       // wave id 0..7
  const int q    = lane >> 4;      // 0..3 (k-quarter)
  const int cl   = lane & 15;      // 0..15
  const int rb   = w * 16 + cl;    // batch row this lane feeds (B operand)

  const float* wrow = wp + (size_t)(g0 + cl) * LAT;  // A row (group g0+cl)
  const int4*  zw   = zlin + (size_t)w * 64 + lane;  // stride 512 per kk-step
  const int kq = q * 8;

  f32x4 acc = {0.f, 0.f, 0.f, 0.f};

  // ---- prologue: tile 0 in flight (no clamp needed: k <= 56+8) ----
  float4 wa0 = *(const float4*)(wrow + kq);
  float4 wa1 = *(const float4*)(wrow + kq + 4);
  float4 wb0 = *(const float4*)(wrow + 32 + kq);
  float4 wb1 = *(const float4*)(wrow + 32 + kq + 4);
  int4 z0 = zw[0];
  int4 z1 = zw[512];

  // ---- barrier-free, LDS-free k-loop ----
#pragma unroll 2
  for (int kt = 0; kt < NKT; ++kt) {
    // prefetch tile kt+1 (wrap on last iter: dead loads, values unused)
    const int tn = (kt + 1 < NKT) ? (kt + 1) : 0;
    int ka = tn * 64 + kq;
    int kb = tn * 64 + 32 + kq;
    ka = (ka > LAT - 8) ? (LAT - 8) : ka;   // in-row clamp; z pad zeroes it
    kb = (kb > LAT - 8) ? (LAT - 8) : kb;
    float4 na0 = *(const float4*)(wrow + ka);
    float4 na1 = *(const float4*)(wrow + ka + 4);
    float4 nb0 = *(const float4*)(wrow + kb);
    float4 nb1 = *(const float4*)(wrow + kb + 4);
    int4 nz0 = zw[(size_t)(tn * 2 + 0) * 512];
    int4 nz1 = zw[(size_t)(tn * 2 + 1) * 512];

    // compute tile kt
    acc = __builtin_amdgcn_mfma_f32_16x16x32_bf16(
        cvt8(wa0, wa1), __builtin_bit_cast(bf16x8, z0), acc, 0, 0, 0);
    acc = __builtin_amdgcn_mfma_f32_16x16x32_bf16(
        cvt8(wb0, wb1), __builtin_bit_cast(bf16x8, z1), acc, 0, 0, 0);

    // rotate pipeline registers (SSA, no arrays)
    wa0 = na0; wa1 = na1; wb0 = nb0; wb1 = nb1;
    z0 = nz0; z1 = nz1;
  }

  // ---- h -> LDS (D layout: row q*4+r = local group, col = batch rb) ----
#pragma unroll
  for (int r = 0; r < 4; ++r)
    h_raw[(q * 4 + r) * HR_STRIDE + rb] = acc[r];
  __syncthreads();

  // ---- BN stats: 512 threads = 16 groups x 32 batch-quads ----
  {
    const int gl = tid >> 5;                 // local group 0..15
    const int bb = (tid & 31) * 4;           // batch base 0..124
    const float4 a = *(const float4*)&h_raw[gl * HR_STRIDE + bb];
    float sm = a.x + a.y + a.z + a.w;
    float sq = a.x * a.x + a.y * a.y + a.z * a.z + a.w * a.w;
#pragma unroll
    for (int m = 1; m < 32; m <<= 1) {
      sm += __shfl_xor(sm, m);
      sq += __shfl_xor(sq, m);
    }
    if ((tid & 31) == 0) {
      float mean = sm * (1.f / 128.f);
      float var  = sq * (1.f / 128.f) - mean * mean;
      var = (var < 0.f) ? 0.f : var;
      float inv   = __builtin_amdgcn_rsqf(var + EPSV);
      float scale = inv * gammap[g0 + gl];
      scale_s[gl] = scale;
      shift_s[gl] = betap[g0 + gl] - mean * scale;
    }
  }
  __syncthreads();

  // ---- expansion: 480 threads = 6 batch rows x 80 float4 columns.
  // A wave's store covers 1024 contiguous output bytes. ----
  if (tid < 480) {
    const int col4 = tid % 80;           // float4 column in 1280-B window row
    const int r0   = tid / 80;           // 0..5
    const int gl   = col4 / 5;           // local group of this column
    const float4 w4  = cw_s[col4];
    const float  cb  = cb_s[gl];
    const float  scl = scale_s[gl];
    const float  sft = shift_s[gl];
    const float* hsrc = &h_raw[gl * HR_STRIDE];
    float* obase = out + (size_t)g0 * KW + (size_t)col4 * 4;
    for (int j = 0; j < 22; ++j) {       // ceil(128/6) passes
      const int row = j * 6 + r0;        // batch index
      if (row < BATCH) {
        float h = hsrc[row];
        h = fmaf(h, scl, sft);
        h = fmaxf(h, h * 0.1f);          // leaky(0.1)
        float y0 = fmaf(h, w4.x, cb);
        float y1 = fmaf(h, w4.y, cb);
        float y2 = fmaf(h, w4.z, cb);
        float y3 = fmaf(h, w4.w, cb);
        y0 = fmaxf(y0, y0 * 0.1f);
        y1 = fmaxf(y1, y1 * 0.1f);
        y2 = fmaxf(y2, y2 * 0.1f);
        y3 = fmaxf(y3, y3 * 0.1f);
        float4 ov;
        ov.x = __builtin_amdgcn_rcpf(1.f + exp2f(y0 * -1.44269504f));
        ov.y = __builtin_amdgcn_rcpf(1.f + exp2f(y1 * -1.44269504f));
        ov.z = __builtin_amdgcn_rcpf(1.f + exp2f(y2 * -1.44269504f));
        ov.w = __builtin_amdgcn_rcpf(1.f + exp2f(y3 * -1.44269504f));
        *(float4*)(obase + (size_t)row * OUTW) = ov;
      }
    }
  }
}

// =====================================================================
// Fallback: fused kernel (used only if ws is too small). Reads z directly.
// =====================================================================
#define BKF 64
__global__ __launch_bounds__(256, 2) void fused_decoder_kernel(
    const float* __restrict__ zp, const float* __restrict__ wp,
    const float* __restrict__ gammap, const float* __restrict__ betap,
    const float* __restrict__ convwp, const float* __restrict__ convbp,
    float* __restrict__ out) {
  const int tid = threadIdx.x;
  const int g0  = blockIdx.x * 32;

  __shared__ ushort As[BATCH * BKF];
  __shared__ ushort Bs[32 * BKF];
  __shared__ float statS[2][2][16];
  __shared__ float statQ[2][2][16];

  const int lane = tid & 63;
  const int w    = tid >> 6;
  const int wm   = w & 1;
  const int wn   = w >> 1;
  const int q    = lane >> 4;
  const int cl   = lane & 15;

  f32x4 acc[4];
  const f32x4 vzero = {0.f, 0.f, 0.f, 0.f};
#pragma unroll
  for (int i = 0; i < 4; ++i) acc[i] = vzero;

  for (int it = 0; it < 32; ++it) {
    const int k0 = it * BKF;
    __syncthreads();
#pragma unroll
    for (int i = 0; i < 4; ++i) {
      int c = i * 256 + tid;
      int r = c >> 3, sc = c & 7;
      int gk = k0 + sc * 8;
      int4 v = make_int4(0, 0, 0, 0);
      if (gk < LAT) v = pack8(zp + (size_t)r * LAT + gk);
      *(int4*)&As[r * BKF + ((sc ^ (r & 7)) << 3)] = v;
    }
    {
      int r = tid >> 3, sc = tid & 7;
      int g  = g0 + r;
      int gk = k0 + sc * 8;
      int4 v = make_int4(0, 0, 0, 0);
      if (gk < LAT && g < NG) v = pack8(wp + (size_t)g * LAT + gk);
      *(int4*)&Bs[r * BKF + ((sc ^ (r & 7)) << 3)] = v;
    }
    __syncthreads();
#pragma unroll
    for (int kk = 0; kk < 2; ++kk) {
      int sc = kk * 4 + q;
      bf16x8 af[4], bfr;
#pragma unroll
      for (int mt = 0; mt < 4; ++mt) {
        int ra = wm * 64 + mt * 16 + cl;
        af[mt] = *(const bf16x8*)&As[ra * BKF + ((sc ^ (ra & 7)) << 3)];
      }
      {
        int rbx = wn * 16 + cl;
        bfr = *(const bf16x8*)&Bs[rbx * BKF + ((sc ^ (rbx & 7)) << 3)];
      }
#pragma unroll
      for (int mt = 0; mt < 4; ++mt)
        acc[mt] = __builtin_amdgcn_mfma_f32_16x16x32_bf16(af[mt], bfr,
                                                          acc[mt], 0, 0, 0);
    }
  }

  float s = 0.f, ss = 0.f;
#pragma unroll
  for (int mt = 0; mt < 4; ++mt)
#pragma unroll
    for (int r = 0; r < 4; ++r) {
      float v = acc[mt][r];
      s += v; ss += v * v;
    }
  s += __shfl_xor(s, 16); ss += __shfl_xor(ss, 16);
  s += __shfl_xor(s, 32); ss += __shfl_xor(ss, 32);
  if (q == 0) { statS[wm][wn][cl] = s; statQ[wm][wn][cl] = ss; }
  __syncthreads();

  const int gcol = g0 + wn * 16 + cl;
  const int gc   = (gcol < NG) ? gcol : (NG - 1);
  float S = statS[0][wn][cl] + statS[1][wn][cl];
  float Q = statQ[0][wn][cl] + statQ[1][wn][cl];
  float mean = S * (1.f / 128.f);
  float var  = Q * (1.f / 128.f) - mean * mean;
  var = (var < 0.f) ? 0.f : var;
  float inv = __builtin_amdgcn_rsqf(var + EPSV);
  float ga = gammap[gc], be = betap[gc], cb = convbp[gc];
  float wv[KW];
  {
    const float4* pw = (const float4*)(convwp + (size_t)gc * KW);
#pragma unroll
    for (int j = 0; j < 5; ++j) {
      float4 f = pw[j];
      wv[4 * j] = f.x; wv[4 * j + 1] = f.y;
      wv[4 * j + 2] = f.z; wv[4 * j + 3] = f.w;
    }
  }
  float scale = inv * ga;
  float shift = be - mean * scale;
  const bool ok = (gcol < NG);
#pragma unroll
  for (int mt = 0; mt < 4; ++mt) {
#pragma unroll
    for (int r = 0; r < 4; ++r) {
      float h = acc[mt][r] * scale + shift;
      h = fmaxf(h, h * 0.1f);
      int b = wm * 64 + mt * 16 + q * 4 + r;
      float4 ov[5];
#pragma unroll
      for (int j = 0; j < 5; ++j) {
        float y0 = h * wv[4 * j]     + cb;
        float y1 = h * wv[4 * j + 1] + cb;
        float y2 = h * wv[4 * j + 2] + cb;
        float y3 = h * wv[4 * j + 3] + cb;
        y0 = fmaxf(y0, y0 * 0.1f);
        y1 = fmaxf(y1, y1 * 0.1f);
        y2 = fmaxf(y2, y2 * 0.1f);
        y3 = fmaxf(y3, y3 * 0.1f);
        ov[j].x = __builtin_amdgcn_rcpf(1.f + exp2f(y0 * -1.44269504f));
        ov[j].y = __builtin_amdgcn_rcpf(1.f + exp2f(y1 * -1.44269504f));
        ov[j].z = __builtin_amdgcn_rcpf(1.f + exp2f(y2 * -1.44269504f));
        ov[j].w = __builtin_amdgcn_rcpf(1.f + exp2f(y3 * -1.44269504f));
      }
      if (ok) {
        float4* po = (float4*)(out + (size_t)b * OUTW + (size_t)gcol * KW);
#pragma unroll
        for (int j = 0; j < 5; ++j) po[j] = ov[j];
      }
    }
  }
}

extern "C" void kernel_launch(void* const* d_in, const int* in_sizes, int n_in,
                              void* d_out, int out_size, void* d_ws, size_t ws_size,
                              hipStream_t stream) {
  const float* z     = (const float*)d_in[0];
  const float* W     = (const float*)d_in[1];
  // d_in[2] = b_fc: unused — cancels under training-mode batchnorm
  const float* gamma = (const float*)d_in[3];
  const float* beta  = (const float*)d_in[4];
  const float* convw = (const float*)d_in[5];
  const float* convb = (const float*)d_in[6];
  float* out = (float*)d_out;

  const size_t zlin_bytes = (size_t)BATCH * 256 * 16;   // 512 KB

  if (ws_size >= zlin_bytes) {
    int4* zlin = (int4*)d_ws;
    zprep_kernel<<<128, 256, 0, stream>>>(z, zlin);     // 32768 chunks
    fused16_kernel<<<NG / EG, 512, 0, stream>>>(zlin, W, gamma, beta,
                                                convw, convb, out);
  } else {
    fused_decoder_kernel<<<(NG + 31) / 32, 256, 0, stream>>>(
        z, W, gamma, beta, convw, convb, out);
  }
}

// Round 7
// 198.679 us; speedup vs baseline: 1.2654x; 1.2654x over previous
//
#include <hip/hip_runtime.h>
#include <hip/hip_bf16.h>
#include <stdint.h>

// Problem constants (all inputs & output are FP32 per the reference file)
#define BATCH 128
#define LAT   2000
#define NG    10000
#define KW    20
#define OUTW  (NG * KW)   // 200000
#define EPSV  1e-5f

#define NKT   32            // 64-wide k-tiles in padded z/W (2048 = 32*64)
#define EG    16            // groups per block (NG = 625 * 16 exactly)
#define WPAD  2056          // W LDS row stride (bf16): +16B pad, 16B-aligned rows
#define HR_STRIDE 132       // h LDS row stride (floats): <=2-way bank alias

typedef __bf16 bf16x8 __attribute__((ext_vector_type(8)));
typedef float  f32x4  __attribute__((ext_vector_type(4)));

__device__ __forceinline__ ushort f2bf(float f) {
  uint32_t u = __builtin_bit_cast(uint32_t, f);
  u = (u + 0x7FFFu + ((u >> 16) & 1u)) >> 16;  // RNE
  return (ushort)u;
}

__device__ __forceinline__ int4 pack8(const float* p) {
  float4 f0 = *(const float4*)p;
  float4 f1 = *(const float4*)(p + 4);
  int4 v;
  v.x = (int)((uint32_t)f2bf(f0.x) | ((uint32_t)f2bf(f0.y) << 16));
  v.y = (int)((uint32_t)f2bf(f0.z) | ((uint32_t)f2bf(f0.w) << 16));
  v.z = (int)((uint32_t)f2bf(f1.x) | ((uint32_t)f2bf(f1.y) << 16));
  v.w = (int)((uint32_t)f2bf(f1.z) | ((uint32_t)f2bf(f1.w) << 16));
  return v;
}

// =====================================================================
// Phase 0: z (128 x 2000 f32) -> bf16 image permuted to WAVE-COALESCED
// fragment order: chunk index ((kt*2+kk)*8 + wave)*64 + q*16 + cl holds
// z[wave*16+cl][kt*64 + kk*32 + q*8 .. +8]. In the GEMM, a wave's 64
// lanes (lane = q*16+cl) read 64 CONSECUTIVE chunks -> 1 KB coalesced.
// Zero-padded above k=2000 (this zero-ness also covers the W tail).
// =====================================================================
__global__ __launch_bounds__(256) void zprep_kernel(
    const float* __restrict__ zp, int4* __restrict__ zlin) {
  const int cg = blockIdx.x * 256 + threadIdx.x;   // 0..32767
  const int r  = cg >> 8;        // batch row 0..127
  const int ck = cg & 255;       // 16B chunk in row; k0 = ck*8
  const int k0 = ck * 8;
  int4 v = make_int4(0, 0, 0, 0);
  if (k0 < LAT) v = pack8(zp + (size_t)r * LAT + k0);  // LAT%8==0: no straddle
  const int kt = ck >> 3, kk = (ck >> 2) & 1, q = ck & 3;
  const int dst = ((kt * 2 + kk) * 8 + (r >> 4)) * 64 + q * 16 + (r & 15);
  zlin[dst] = v;
}

// =====================================================================
// Fused pipeline (round-5 structure + DEPTH-4 z prefetch).
// One block = 16 groups x all 128 batches; 512 threads = 8 waves, wave w
// owns batches w*16..w*16+15.
//   Stage 1 (once): all 16 W rows (128 KB f32, coalesced) -> padded bf16
//     LDS image (row stride WPAD, no XOR: pad gives <=2-way reads). One
//     barrier.
//   Stage 2 (k-loop, NO barriers): B-frags from the permuted z image,
//     prefetched 4 TILES AHEAD in named registers (8 int4 in flight =
//     8 KB/wave outstanding; 16 waves/CU -> the L2 stream saturates
//     instead of stalling at depth-1). A-frags via ds_read_b128.
//   Stage 3: h -> LDS -> BN stats -> store-coalesced expand (2 barriers).
// =====================================================================
__global__ __launch_bounds__(512, 2) void fused16_kernel(
    const int4* __restrict__ zlin, const float* __restrict__ wp,
    const float* __restrict__ gammap, const float* __restrict__ betap,
    const float* __restrict__ convwp, const float* __restrict__ convbp,
    float* __restrict__ out) {
  const int tid = threadIdx.x;
  const int g0  = blockIdx.x * EG;

  __shared__ __attribute__((aligned(16))) ushort Wl[EG * WPAD];  // ~64.3 KB
  __shared__ float  h_raw[EG * HR_STRIDE];   // raw (pre-BN) h
  __shared__ float4 cw_s[EG * 5];            // conv_w window
  __shared__ float  cb_s[EG];
  __shared__ float  scale_s[EG];
  __shared__ float  shift_s[EG];

  if (tid < EG * 5)
    cw_s[tid] = *(const float4*)(convwp + (size_t)g0 * KW + tid * 4);
  if (tid < EG) cb_s[tid] = convbp[g0 + tid];

  // ---- stage ALL W rows: 4096 16B-chunks, 8/thread, coalesced reads.
  // LDS layout: row*WPAD + kt*64 + j*8 (linear; row pad staggers banks).
#pragma unroll
  for (int i = 0; i < 8; ++i) {
    int cc  = i * 512 + tid;     // 0..4095
    int row = cc >> 8;           // local group 0..15
    int c   = cc & 255;          // chunk in row
    int kt  = c >> 3, j = c & 7;
    int k0  = kt * 64 + j * 8;
    int4 v  = make_int4(0, 0, 0, 0);
    if (k0 < LAT) v = pack8(wp + (size_t)(g0 + row) * LAT + k0);
    *(int4*)&Wl[row * WPAD + kt * 64 + j * 8] = v;
  }

  const int lane = tid & 63;
  const int w    = tid >> 6;       // wave id 0..7
  const int q    = lane >> 4;      // 0..3 (k-quarter)
  const int cl   = lane & 15;      // 0..15
  const int rb   = w * 16 + cl;    // batch row this lane feeds (B operand)

  const int4* zw = zlin + (size_t)w * 64 + lane;   // +512 per kk-step
  const ushort* wl = &Wl[cl * WPAD];               // A row base (group g0+cl)

  f32x4 acc = {0.f, 0.f, 0.f, 0.f};

  // ---- prologue: z tiles 0..3 in flight (depth 4, 8 KB/wave) ----
  int4 za0 = zw[0],    za1 = zw[512];
  int4 zb0 = zw[1024], zb1 = zw[1536];
  int4 zc0 = zw[2048], zc1 = zw[2560];
  int4 zd0 = zw[3072], zd1 = zw[3584];

  __syncthreads();   // W image ready (z prefetch overlapped the stage)

  // ---- barrier-free k-loop: consume oldest tile, prefetch kt+4 ----
#pragma unroll 4
  for (int kt = 0; kt < NKT; ++kt) {
    const int tp = (kt + 4 < NKT) ? (kt + 4) : kt;   // tail: dead reload
    int4 ne0 = zw[(size_t)(tp * 2 + 0) * 512];
    int4 ne1 = zw[(size_t)(tp * 2 + 1) * 512];

    bf16x8 a0 = *(const bf16x8*)&wl[kt * 64 + q * 8];        // kk=0
    bf16x8 a1 = *(const bf16x8*)&wl[kt * 64 + (4 + q) * 8];  // kk=1

    acc = __builtin_amdgcn_mfma_f32_16x16x32_bf16(
        a0, __builtin_bit_cast(bf16x8, za0), acc, 0, 0, 0);
    acc = __builtin_amdgcn_mfma_f32_16x16x32_bf16(
        a1, __builtin_bit_cast(bf16x8, za1), acc, 0, 0, 0);

    // rotate depth-4 pipeline (SSA renaming under unroll, no arrays)
    za0 = zb0; za1 = zb1;
    zb0 = zc0; zb1 = zc1;
    zc0 = zd0; zc1 = zd1;
    zd0 = ne0; zd1 = ne1;
  }

  // ---- h -> LDS (D layout: row q*4+r = local group, col = batch rb) ----
#pragma unroll
  for (int r = 0; r < 4; ++r)
    h_raw[(q * 4 + r) * HR_STRIDE + rb] = acc[r];
  __syncthreads();

  // ---- BN stats: 512 threads = 16 groups x 32 batch-quads ----
  {
    const int gl = tid >> 5;                 // local group 0..15
    const int bb = (tid & 31) * 4;           // batch base 0..124
    const float4 a = *(const float4*)&h_raw[gl * HR_STRIDE + bb];
    float sm = a.x + a.y + a.z + a.w;
    float sq = a.x * a.x + a.y * a.y + a.z * a.z + a.w * a.w;
#pragma unroll
    for (int m = 1; m < 32; m <<= 1) {
      sm += __shfl_xor(sm, m);
      sq += __shfl_xor(sq, m);
    }
    if ((tid & 31) == 0) {
      float mean = sm * (1.f / 128.f);
      float var  = sq * (1.f / 128.f) - mean * mean;
      var = (var < 0.f) ? 0.f : var;
      float inv   = __builtin_amdgcn_rsqf(var + EPSV);
      float scale = inv * gammap[g0 + gl];
      scale_s[gl] = scale;
      shift_s[gl] = betap[g0 + gl] - mean * scale;
    }
  }
  __syncthreads();

  // ---- expansion: 480 threads = 6 batch rows x 80 float4 columns.
  // A wave's store covers 1024 contiguous output bytes. ----
  if (tid < 480) {
    const int col4 = tid % 80;           // float4 column in 1280-B window row
    const int r0   = tid / 80;           // 0..5
    const int gl   = col4 / 5;           // local group of this column
    const float4 w4  = cw_s[col4];
    const float  cb  = cb_s[gl];
    const float  scl = scale_s[gl];
    const float  sft = shift_s[gl];
    const float* hsrc = &h_raw[gl * HR_STRIDE];
    float* obase = out + (size_t)g0 * KW + (size_t)col4 * 4;
    for (int j = 0; j < 22; ++j) {       // ceil(128/6) passes
      const int row = j * 6 + r0;        // batch index
      if (row < BATCH) {
        float h = hsrc[row];
        h = fmaf(h, scl, sft);
        h = fmaxf(h, h * 0.1f);          // leaky(0.1)
        float y0 = fmaf(h, w4.x, cb);
        float y1 = fmaf(h, w4.y, cb);
        float y2 = fmaf(h, w4.z, cb);
        float y3 = fmaf(h, w4.w, cb);
        y0 = fmaxf(y0, y0 * 0.1f);
        y1 = fmaxf(y1, y1 * 0.1f);
        y2 = fmaxf(y2, y2 * 0.1f);
        y3 = fmaxf(y3, y3 * 0.1f);
        float4 ov;
        ov.x = __builtin_amdgcn_rcpf(1.f + exp2f(y0 * -1.44269504f));
        ov.y = __builtin_amdgcn_rcpf(1.f + exp2f(y1 * -1.44269504f));
        ov.z = __builtin_amdgcn_rcpf(1.f + exp2f(y2 * -1.44269504f));
        ov.w = __builtin_amdgcn_rcpf(1.f + exp2f(y3 * -1.44269504f));
        *(float4*)(obase + (size_t)row * OUTW) = ov;
      }
    }
  }
}

// =====================================================================
// Fallback: fused kernel (used only if ws is too small). Reads z directly.
// =====================================================================
#define BKF 64
__global__ __launch_bounds__(256, 2) void fused_decoder_kernel(
    const float* __restrict__ zp, const float* __restrict__ wp,
    const float* __restrict__ gammap, const float* __restrict__ betap,
    const float* __restrict__ convwp, const float* __restrict__ convbp,
    float* __restrict__ out) {
  const int tid = threadIdx.x;
  const int g0  = blockIdx.x * 32;

  __shared__ ushort As[BATCH * BKF];
  __shared__ ushort Bs[32 * BKF];
  __shared__ float statS[2][2][16];
  __shared__ float statQ[2][2][16];

  const int lane = tid & 63;
  const int w    = tid >> 6;
  const int wm   = w & 1;
  const int wn   = w >> 1;
  const int q    = lane >> 4;
  const int cl   = lane & 15;

  f32x4 acc[4];
  const f32x4 vzero = {0.f, 0.f, 0.f, 0.f};
#pragma unroll
  for (int i = 0; i < 4; ++i) acc[i] = vzero;

  for (int it = 0; it < 32; ++it) {
    const int k0 = it * BKF;
    __syncthreads();
#pragma unroll
    for (int i = 0; i < 4; ++i) {
      int c = i * 256 + tid;
      int r = c >> 3, sc = c & 7;
      int gk = k0 + sc * 8;
      int4 v = make_int4(0, 0, 0, 0);
      if (gk < LAT) v = pack8(zp + (size_t)r * LAT + gk);
      *(int4*)&As[r * BKF + ((sc ^ (r & 7)) << 3)] = v;
    }
    {
      int r = tid >> 3, sc = tid & 7;
      int g  = g0 + r;
      int gk = k0 + sc * 8;
      int4 v = make_int4(0, 0, 0, 0);
      if (gk < LAT && g < NG) v = pack8(wp + (size_t)g * LAT + gk);
      *(int4*)&Bs[r * BKF + ((sc ^ (r & 7)) << 3)] = v;
    }
    __syncthreads();
#pragma unroll
    for (int kk = 0; kk < 2; ++kk) {
      int sc = kk * 4 + q;
      bf16x8 af[4], bfr;
#pragma unroll
      for (int mt = 0; mt < 4; ++mt) {
        int ra = wm * 64 + mt * 16 + cl;
        af[mt] = *(const bf16x8*)&As[ra * BKF + ((sc ^ (ra & 7)) << 3)];
      }
      {
        int rbx = wn * 16 + cl;
        bfr = *(const bf16x8*)&Bs[rbx * BKF + ((sc ^ (rbx & 7)) << 3)];
      }
#pragma unroll
      for (int mt = 0; mt < 4; ++mt)
        acc[mt] = __builtin_amdgcn_mfma_f32_16x16x32_bf16(af[mt], bfr,
                                                          acc[mt], 0, 0, 0);
    }
  }

  float s = 0.f, ss = 0.f;
#pragma unroll
  for (int mt = 0; mt < 4; ++mt)
#pragma unroll
    for (int r = 0; r < 4; ++r) {
      float v = acc[mt][r];
      s += v; ss += v * v;
    }
  s += __shfl_xor(s, 16); ss += __shfl_xor(ss, 16);
  s += __shfl_xor(s, 32); ss += __shfl_xor(ss, 32);
  if (q == 0) { statS[wm][wn][cl] = s; statQ[wm][wn][cl] = ss; }
  __syncthreads();

  const int gcol = g0 + wn * 16 + cl;
  const int gc   = (gcol < NG) ? gcol : (NG - 1);
  float S = statS[0][wn][cl] + statS[1][wn][cl];
  float Q = statQ[0][wn][cl] + statQ[1][wn][cl];
  float mean = S * (1.f / 128.f);
  float var  = Q * (1.f / 128.f) - mean * mean;
  var = (var < 0.f) ? 0.f : var;
  float inv = __builtin_amdgcn_rsqf(var + EPSV);
  float ga = gammap[gc], be = betap[gc], cb = convbp[gc];
  float wv[KW];
  {
    const float4* pw = (const float4*)(convwp + (size_t)gc * KW);
#pragma unroll
    for (int j = 0; j < 5; ++j) {
      float4 f = pw[j];
      wv[4 * j] = f.x; wv[4 * j + 1] = f.y;
      wv[4 * j + 2] = f.z; wv[4 * j + 3] = f.w;
    }
  }
  float scale = inv * ga;
  float shift = be - mean * scale;
  const bool ok = (gcol < NG);
#pragma unroll
  for (int mt = 0; mt < 4; ++mt) {
#pragma unroll
    for (int r = 0; r < 4; ++r) {
      float h = acc[mt][r] * scale + shift;
      h = fmaxf(h, h * 0.1f);
      int b = wm * 64 + mt * 16 + q * 4 + r;
      float4 ov[5];
#pragma unroll
      for (int j = 0; j < 5; ++j) {
        float y0 = h * wv[4 * j]     + cb;
        float y1 = h * wv[4 * j + 1] + cb;
        float y2 = h * wv[4 * j + 2] + cb;
        float y3 = h * wv[4 * j + 3] + cb;
        y0 = fmaxf(y0, y0 * 0.1f);
        y1 = fmaxf(y1, y1 * 0.1f);
        y2 = fmaxf(y2, y2 * 0.1f);
        y3 = fmaxf(y3, y3 * 0.1f);
        ov[j].x = __builtin_amdgcn_rcpf(1.f + exp2f(y0 * -1.44269504f));
        ov[j].y = __builtin_amdgcn_rcpf(1.f + exp2f(y1 * -1.44269504f));
        ov[j].z = __builtin_amdgcn_rcpf(1.f + exp2f(y2 * -1.44269504f));
        ov[j].w = __builtin_amdgcn_rcpf(1.f + exp2f(y3 * -1.44269504f));
      }
      if (ok) {
        float4* po = (float4*)(out + (size_t)b * OUTW + (size_t)gcol * KW);
#pragma unroll
        for (int j = 0; j < 5; ++j) po[j] = ov[j];
      }
    }
  }
}

extern "C" void kernel_launch(void* const* d_in, const int* in_sizes, int n_in,
                              void* d_out, int out_size, void* d_ws, size_t ws_size,
                              hipStream_t stream) {
  const float* z     = (const float*)d_in[0];
  const float* W     = (const float*)d_in[1];
  // d_in[2] = b_fc: unused — cancels under training-mode batchnorm
  const float* gamma = (const float*)d_in[3];
  const float* beta  = (const float*)d_in[4];
  const float* convw = (const float*)d_in[5];
  const float* convb = (const float*)d_in[6];
  float* out = (float*)d_out;

  const size_t zlin_bytes = (size_t)BATCH * 256 * 16;   // 512 KB

  if (ws_size >= zlin_bytes) {
    int4* zlin = (int4*)d_ws;
    zprep_kernel<<<128, 256, 0, stream>>>(z, zlin);     // 32768 chunks
    fused16_kernel<<<NG / EG, 512, 0, stream>>>(zlin, W, gamma, beta,
                                                convw, convb, out);
  } else {
    fused_decoder_kernel<<<(NG + 31) / 32, 256, 0, stream>>>(
        z, W, gamma, beta, convw, convb, out);
  }
}